// Round 4
// baseline (153.768 us; speedup 1.0000x reference)
//
#include <hip/hip_runtime.h>
#include <hip/hip_bf16.h>

#define BATCH 8
#define NN    2048
#define FF    256
#define LL    16

typedef float f32x4 __attribute__((ext_vector_type(4)));
typedef short s16x8 __attribute__((ext_vector_type(8)));

static __device__ __forceinline__ unsigned short f2bf(float f) {
    return __builtin_bit_cast(unsigned short, __float2bfloat16(f));
}
static __device__ __forceinline__ float bf2f(unsigned short u) {
    unsigned int x = ((unsigned int)u) << 16;
    return __builtin_bit_cast(float, x);
}

// ---------------------------------------------------------------------------
// Kernel A (fused): per 32-row tile: stage x bf16 -> LDS; z = proj MFMA;
// z/sq -> global (sq from the SAME bf16 z => exact diagonal); pi = MLP MFMA;
// xT transpose write (64B-line coalesced). Grid 8*64=512 (2 blocks/CU), 256thr.
// ---------------------------------------------------------------------------
__global__ __launch_bounds__(256) void fused_a_kernel(
    const float* __restrict__ x,
    const float* __restrict__ proj_w, const float* __restrict__ proj_b,
    const float* __restrict__ pi_w1,  const float* __restrict__ pi_b1,
    const float* __restrict__ pi_w2,  const float* __restrict__ pi_b2,
    unsigned short* __restrict__ xT,
    unsigned short* __restrict__ zbG,
    float* __restrict__ sqbuf,
    float* __restrict__ pibuf)
{
    const int bid = blockIdx.x;
    const int b = bid & 7, nt = bid >> 3;      // nt 0..63
    const int n0 = nt * 32;
    const int t = threadIdx.x;
    const int wv = t >> 6, ln = t & 63;
    const int kg = ln >> 4, cl = ln & 15;

    const float* xb = x + (size_t)b * NN * FF;
    unsigned short* xTb = xT + (size_t)b * FF * NN;

    __shared__ unsigned short xbsh[32 * 264];   // bf16 x tile
    __shared__ unsigned short Wbsh[16 * 264];   // proj_w bf16 [l][f]
    __shared__ unsigned short W1bsh[256 * 24];  // pi_w1 bf16 [f][l]
    __shared__ unsigned short zbsh[32 * 24];    // z bf16 [n][l]
    __shared__ float b1sh[256], w2sh[256], pbsh[16];
    __shared__ float pp[2][32];

    // ---- stage x tile (f32 -> bf16) ----
#pragma unroll
    for (int i = 0; i < 8; ++i) {
        const int slot = i * 256 + t;
        const int r = slot >> 6, c4 = slot & 63;
        const float4 v = *(const float4*)(xb + (size_t)(n0 + r) * FF + c4 * 4);
        ushort4 o; o.x = f2bf(v.x); o.y = f2bf(v.y); o.z = f2bf(v.z); o.w = f2bf(v.w);
        *(ushort4*)&xbsh[r * 264 + c4 * 4] = o;
    }
    // ---- stage proj_w ----
#pragma unroll
    for (int i = 0; i < 4; ++i) {
        const int slot = i * 256 + t;
        const int l = slot >> 6, c4 = slot & 63;
        const float4 v = *(const float4*)(proj_w + l * FF + c4 * 4);
        ushort4 o; o.x = f2bf(v.x); o.y = f2bf(v.y); o.z = f2bf(v.z); o.w = f2bf(v.w);
        *(ushort4*)&Wbsh[l * 264 + c4 * 4] = o;
    }
    // ---- stage pi_w1 ----
#pragma unroll
    for (int i = 0; i < 4; ++i) {
        const int slot = i * 256 + t;
        const int f = slot >> 2, q = slot & 3;
        const float4 v = *(const float4*)(pi_w1 + f * LL + q * 4);
        ushort4 o; o.x = f2bf(v.x); o.y = f2bf(v.y); o.z = f2bf(v.z); o.w = f2bf(v.w);
        *(ushort4*)&W1bsh[f * 24 + q * 4] = o;
    }
    b1sh[t] = pi_b1[t];
    w2sh[t] = pi_w2[t];
    if (t < 16) pbsh[t] = proj_b[t];
    __syncthreads();

    // ---- proj MFMA (waves 0,1; wave w -> rows w*16..+16) ----
    if (wv < 2) {
        f32x4 zacc = {0.f, 0.f, 0.f, 0.f};
#pragma unroll
        for (int g = 0; g < 8; ++g) {
            const s16x8 af = *(const s16x8*)&xbsh[(wv * 16 + cl) * 264 + g * 32 + kg * 8];
            const s16x8 bf = *(const s16x8*)&Wbsh[cl * 264 + g * 32 + kg * 8];
            zacc = __builtin_amdgcn_mfma_f32_16x16x32_bf16(af, bf, zacc, 0, 0, 0);
        }
        const float pb = pbsh[cl];
#pragma unroll
        for (int r = 0; r < 4; ++r)
            zbsh[(wv * 16 + kg * 4 + r) * 24 + cl] = f2bf(zacc[r] + pb);
    }
    __syncthreads();

    // ---- z -> global (bf16), sq from bf16 z ----
    if (t < 32) {
        unsigned short zr[16]; float sq = 0.f;
#pragma unroll
        for (int l = 0; l < 16; ++l) {
            zr[l] = zbsh[t * 24 + l];
            const float zf = bf2f(zr[l]);
            sq = fmaf(zf, zf, sq);
        }
        unsigned short* dst = zbG + ((size_t)b * NN + n0 + t) * 16;
        *(uint4*)dst = *(uint4*)&zr[0];
        *(uint4*)(dst + 8) = *(uint4*)&zr[8];
        sqbuf[(size_t)b * NN + n0 + t] = sq;
    }

    // ---- MLP via MFMA: wave -> (ntile = wv&1, f-chunk = wv>>1) ----
    {
        const int ntl = wv & 1;
        s16x8 bz = {0, 0, 0, 0, 0, 0, 0, 0};
        if (kg < 2) bz = *(const s16x8*)&zbsh[(ntl * 16 + cl) * 24 + kg * 8];
        float pisum = 0.f;
        const f32x4 zf4 = {0.f, 0.f, 0.f, 0.f};
#pragma unroll
        for (int j = 0; j < 8; ++j) {
            const int ft = (wv >> 1) * 8 + j;
            s16x8 aw = {0, 0, 0, 0, 0, 0, 0, 0};
            if (kg < 2) aw = *(const s16x8*)&W1bsh[(ft * 16 + cl) * 24 + kg * 8];
            const f32x4 h4 = __builtin_amdgcn_mfma_f32_16x16x32_bf16(aw, bz, zf4, 0, 0, 0);
#pragma unroll
            for (int r = 0; r < 4; ++r) {
                const int f = ft * 16 + kg * 4 + r;
                const float h = fmaxf(h4[r] + b1sh[f], 0.f);
                pisum = fmaf(h, w2sh[f], pisum);
            }
        }
        pisum += __shfl_xor(pisum, 16, 64);
        pisum += __shfl_xor(pisum, 32, 64);
        if (ln < 16) pp[wv >> 1][ntl * 16 + ln] = pisum;
    }
    __syncthreads();

    if (t < 32) {
        const float tp = pp[0][t] + pp[1][t] + pi_b2[0];
        pibuf[(size_t)b * NN + n0 + t] = 1.f / (1.f + __expf(-tp));
    }

    // ---- transpose write: per inst, 8 f-rows x 32 n = 8 x 64B lines ----
#pragma unroll
    for (int it = 0; it < 8; ++it) {
        const int f = wv * 64 + it * 8 + (ln >> 3);
        const int q = ln & 7;
        ushort4 o;
        o.x = xbsh[(q * 4 + 0) * 264 + f];
        o.y = xbsh[(q * 4 + 1) * 264 + f];
        o.z = xbsh[(q * 4 + 2) * 264 + f];
        o.w = xbsh[(q * 4 + 3) * 264 + f];
        *(ushort4*)(xTb + (size_t)f * NN + n0 + q * 4) = o;
    }
}

// ---------------------------------------------------------------------------
// Kernel Q: q[n] = sum_m exp(2 z_n.z_m - sq_n - sq_m) via register-only gram
// MFMA (no LDS in loop, no barriers). 32n/block, 256thr, grid 512 (2/CU).
// ---------------------------------------------------------------------------
__global__ __launch_bounds__(256) void qc_kernel(
    const unsigned short* __restrict__ zbG,
    const float* __restrict__ sqbuf,
    const float* __restrict__ pibuf,
    float* __restrict__ cbuf)
{
    const int bid = blockIdx.x;
    const int b = bid & 7, nt = bid >> 3;
    const int n0 = nt * 32;
    const int t = threadIdx.x;
    const int wv = t >> 6, ln = t & 63;
    const int kg = ln >> 4, cl = ln & 15;

    const unsigned short* zb = zbG + (size_t)b * NN * LL;
    const float* sqb = sqbuf + (size_t)b * NN;
    __shared__ float qq[2][32];

    s16x8 zn = {0, 0, 0, 0, 0, 0, 0, 0};
    if (kg < 2) zn = *(const s16x8*)(zb + (size_t)(n0 + (wv & 1) * 16 + cl) * 16 + kg * 8);
    const float sqn = sqb[n0 + (wv & 1) * 16 + cl];
    const f32x4 zf4 = {0.f, 0.f, 0.f, 0.f};
    float qloc = 0.f;

#pragma unroll 2
    for (int ch = 0; ch < 32; ++ch) {
#pragma unroll
        for (int mi = 0; mi < 2; ++mi) {
            const int mm = ch * 64 + ((wv >> 1) + mi * 2) * 16;
            s16x8 zm = {0, 0, 0, 0, 0, 0, 0, 0};
            if (kg < 2) zm = *(const s16x8*)(zb + (size_t)(mm + cl) * 16 + kg * 8);
            const f32x4 sqm4 = *(const f32x4*)(sqb + mm + kg * 4);
            const f32x4 g = __builtin_amdgcn_mfma_f32_16x16x32_bf16(zm, zn, zf4, 0, 0, 0);
#pragma unroll
            for (int r = 0; r < 4; ++r)
                qloc += __expf(2.f * g[r] - sqm4[r] - sqn);
        }
    }
    qloc += __shfl_xor(qloc, 16, 64);
    qloc += __shfl_xor(qloc, 32, 64);
    if (ln < 16) qq[wv >> 1][(wv & 1) * 16 + ln] = qloc;
    __syncthreads();
    if (t < 32) {
        const size_t gi = (size_t)b * NN + n0 + t;
        cbuf[gi] = pibuf[gi] / (qq[0][t] + qq[1][t]);
    }
}

// ---------------------------------------------------------------------------
// Kernel M: out[n,f] = (1-dt)x[n,f] + 4dt/(rowsum+1e-5)*sum_m w[n,m]x[m,f]
//   w[n,m] = exp(2 z_n.z_m - sq_n - sq_m)*c[m], gram operands SWAPPED
//   (A=z_m, B=z_n -> lane holds 4 consecutive m for one n -> ds_write_b64).
// 64n x 256f tile, 512thr (8 waves), grid 256. All inputs global->reg with
// depth-1 struct double-buffer; only w goes through LDS (16KB, dbuf, XOR
// swizzle); ONE barrier per 64-m chunk, no vmcnt drains.
// ---------------------------------------------------------------------------
struct MRegs {
    s16x8 zm0, zm1;
    f32x4 sqm0, sqm1, cm0, cm1;
    s16x8 a0, a1, a2, a3;
};

__global__ __launch_bounds__(512) void main_kernel(
    const float* __restrict__ x,
    const unsigned short* __restrict__ xT,
    const unsigned short* __restrict__ zbG,
    const float* __restrict__ sqbuf,
    const float* __restrict__ cbuf,
    const float* __restrict__ dtp,
    float* __restrict__ out)
{
    const int bid = blockIdx.x;
    const int b = bid & 7, nt = bid >> 3;      // nt 0..31
    const int n0 = nt * 64;
    const int t = threadIdx.x;
    const int wv = t >> 6, ln = t & 63;
    const int kg = ln >> 4, cl = ln & 15;
    const int nt4 = wv >> 1;                   // phase-1 n-subtile 0..3
    const int mgrp = wv & 1;                   // phase-1 m-tile group

    const float*          xb  = x   + (size_t)b * NN * FF;
    const unsigned short* xTb = xT  + (size_t)b * FF * NN;
    const unsigned short* zb  = zbG + (size_t)b * NN * LL;
    const float*          sqB = sqbuf + (size_t)b * NN;
    const float*          cB  = cbuf  + (size_t)b * NN;
    float*                ob  = out + (size_t)b * NN * FF;

    __shared__ unsigned short wsh[2][64][64];  // 16 KB
    __shared__ float rsp[2][64];

    const float dtv = dtp[0];
    const int nloc = nt4 * 16 + cl;

    // fixed B-frag: z_n rows of this wave's n-subtile
    s16x8 zn = {0, 0, 0, 0, 0, 0, 0, 0};
    if (kg < 2) zn = *(const s16x8*)(zb + (size_t)(n0 + nloc) * 16 + kg * 8);
    const float sqn = sqB[n0 + nloc];
    const f32x4 zf4 = {0.f, 0.f, 0.f, 0.f};

    f32x4 acc[2][4];
#pragma unroll
    for (int fi = 0; fi < 2; ++fi)
#pragma unroll
        for (int ni = 0; ni < 4; ++ni) acc[fi][ni] = (f32x4){0.f, 0.f, 0.f, 0.f};
    float rloc = 0.f;

    auto PRE = [&](MRegs& R, int kt) {
        const int m0 = kt * 64;
        const int mmA = m0 + (mgrp * 2 + 0) * 16;
        const int mmB = m0 + (mgrp * 2 + 1) * 16;
        R.zm0 = (s16x8){0, 0, 0, 0, 0, 0, 0, 0};
        R.zm1 = (s16x8){0, 0, 0, 0, 0, 0, 0, 0};
        if (kg < 2) {
            R.zm0 = *(const s16x8*)(zb + (size_t)(mmA + cl) * 16 + kg * 8);
            R.zm1 = *(const s16x8*)(zb + (size_t)(mmB + cl) * 16 + kg * 8);
        }
        R.sqm0 = *(const f32x4*)(sqB + mmA + kg * 4);
        R.sqm1 = *(const f32x4*)(sqB + mmB + kg * 4);
        R.cm0  = *(const f32x4*)(cB + mmA + kg * 4);
        R.cm1  = *(const f32x4*)(cB + mmB + kg * 4);
        const unsigned short* xr0 = xTb + (size_t)(wv * 32 + cl) * NN + m0;
        const unsigned short* xr1 = xTb + (size_t)(wv * 32 + 16 + cl) * NN + m0;
        R.a0 = *(const s16x8*)(xr0 + kg * 8);          // ks=0, fi=0
        R.a1 = *(const s16x8*)(xr1 + kg * 8);          // ks=0, fi=1
        R.a2 = *(const s16x8*)(xr0 + 32 + kg * 8);     // ks=1, fi=0
        R.a3 = *(const s16x8*)(xr1 + 32 + kg * 8);     // ks=1, fi=1
    };

    auto P1 = [&](const MRegs& R, int cur) {
        char* wb = (char*)wsh + cur * 8192;
#pragma unroll
        for (int j = 0; j < 2; ++j) {
            const s16x8 zm  = j ? R.zm1  : R.zm0;
            const f32x4 sqm = j ? R.sqm1 : R.sqm0;
            const f32x4 cm  = j ? R.cm1  : R.cm0;
            const int mt = mgrp * 2 + j;
            const f32x4 g = __builtin_amdgcn_mfma_f32_16x16x32_bf16(zm, zn, zf4, 0, 0, 0);
            const float w0 = __expf(2.f * g[0] - sqm[0] - sqn) * cm[0];
            const float w1 = __expf(2.f * g[1] - sqm[1] - sqn) * cm[1];
            const float w2 = __expf(2.f * g[2] - sqm[2] - sqn) * cm[2];
            const float w3 = __expf(2.f * g[3] - sqm[3] - sqn) * cm[3];
            rloc += (w0 + w1) + (w2 + w3);
            uint2 val;
            val.x = (unsigned)f2bf(w0) | ((unsigned)f2bf(w1) << 16);
            val.y = (unsigned)f2bf(w2) | ((unsigned)f2bf(w3) << 16);
            const int c16 = mt * 2 + (kg >> 1);
            const int phys = c16 ^ (nloc & 7);
            *(uint2*)(wb + nloc * 128 + phys * 16 + (kg & 1) * 8) = val;
        }
    };

    auto P2 = [&](const MRegs& R, int cur) {
        const char* wb = (const char*)wsh + cur * 8192;
#pragma unroll
        for (int ks = 0; ks < 2; ++ks) {
            s16x8 bw[4];
#pragma unroll
            for (int ni = 0; ni < 4; ++ni) {
                const int nr = ni * 16 + cl;
                const int phys = (ks * 4 + kg) ^ (nr & 7);
                bw[ni] = *(const s16x8*)(wb + nr * 128 + phys * 16);
            }
            const s16x8 aA = ks ? R.a2 : R.a0;
            const s16x8 aB = ks ? R.a3 : R.a1;
#pragma unroll
            for (int ni = 0; ni < 4; ++ni) {
                acc[0][ni] = __builtin_amdgcn_mfma_f32_16x16x32_bf16(aA, bw[ni], acc[0][ni], 0, 0, 0);
                acc[1][ni] = __builtin_amdgcn_mfma_f32_16x16x32_bf16(aB, bw[ni], acc[1][ni], 0, 0, 0);
            }
        }
    };

    MRegs rA, rB;
    PRE(rA, 0);
    for (int kt2 = 0; kt2 < 32; kt2 += 2) {
        PRE(rB, kt2 + 1);
        P1(rA, 0);
        __syncthreads();
        P2(rA, 0);
        if (kt2 + 2 < 32) PRE(rA, kt2 + 2);
        P1(rB, 1);
        __syncthreads();
        P2(rB, 1);
    }

    // rowsum: sum the 4 kg lanes holding the same n, then combine m-groups
    rloc += __shfl_xor(rloc, 16, 64);
    rloc += __shfl_xor(rloc, 32, 64);
    if (ln < 16) rsp[mgrp][nt4 * 16 + ln] = rloc;
    __syncthreads();

    // epilogue: acc D[row=f][col=n]
#pragma unroll
    for (int ni = 0; ni < 4; ++ni) {
        const int nl = ni * 16 + cl;
        const float rstot = rsp[0][nl] + rsp[1][nl] + 1e-5f;
        const float sc = 4.f * dtv / rstot;
        const int ng = n0 + nl;
#pragma unroll
        for (int fi = 0; fi < 2; ++fi) {
            const int fg = wv * 32 + fi * 16 + kg * 4;
            const float4 xv = *(const float4*)(xb + (size_t)ng * FF + fg);
            float4 o;
            o.x = (1.f - dtv) * xv.x + sc * acc[fi][ni][0];
            o.y = (1.f - dtv) * xv.y + sc * acc[fi][ni][1];
            o.z = (1.f - dtv) * xv.z + sc * acc[fi][ni][2];
            o.w = (1.f - dtv) * xv.w + sc * acc[fi][ni][3];
            *(float4*)(ob + (size_t)ng * FF + fg) = o;
        }
    }
}

// ---------------------------------------------------------------------------
extern "C" void kernel_launch(void* const* d_in, const int* in_sizes, int n_in,
                              void* d_out, int out_size, void* d_ws, size_t ws_size,
                              hipStream_t stream) {
    const float* x      = (const float*)d_in[0];
    const float* proj_w = (const float*)d_in[1];
    const float* proj_b = (const float*)d_in[2];
    const float* pi_w1  = (const float*)d_in[3];
    const float* pi_b1  = (const float*)d_in[4];
    const float* pi_w2  = (const float*)d_in[5];
    const float* pi_b2  = (const float*)d_in[6];
    const float* dtp    = (const float*)d_in[7];
    float* out = (float*)d_out;

    // workspace: xT bf16 8MB | z bf16 512KB | sq 64KB | pi 64KB | c 64KB
    unsigned short* xT  = (unsigned short*)d_ws;
    unsigned short* zbG = xT + (size_t)BATCH * FF * NN;
    float* sqbuf = (float*)(zbG + (size_t)BATCH * NN * LL);
    float* pibuf = sqbuf + (size_t)BATCH * NN;
    float* cbuf  = pibuf + (size_t)BATCH * NN;

    fused_a_kernel<<<dim3(BATCH * (NN / 32)), dim3(256), 0, stream>>>(
        x, proj_w, proj_b, pi_w1, pi_b1, pi_w2, pi_b2, xT, zbG, sqbuf, pibuf);

    qc_kernel<<<dim3(BATCH * (NN / 32)), dim3(256), 0, stream>>>(
        zbG, sqbuf, pibuf, cbuf);

    main_kernel<<<dim3(BATCH * (NN / 64)), dim3(512), 0, stream>>>(
        x, xT, zbG, sqbuf, cbuf, dtp, out);
}

// Round 6
// 148.337 us; speedup vs baseline: 1.0366x; 1.0366x over previous
//
#include <hip/hip_runtime.h>
#include <hip/hip_bf16.h>

#define BATCH 8
#define NN    2048
#define FF    256
#define LL    16

typedef float f32x4 __attribute__((ext_vector_type(4)));
typedef short s16x8 __attribute__((ext_vector_type(8)));

static __device__ __forceinline__ unsigned short f2bf(float f) {
    return __builtin_bit_cast(unsigned short, __float2bfloat16(f));
}
static __device__ __forceinline__ float bf2f(unsigned short u) {
    unsigned int x = ((unsigned int)u) << 16;
    return __builtin_bit_cast(float, x);
}

typedef const __attribute__((address_space(1))) unsigned int glb_uint;
typedef __attribute__((address_space(3))) unsigned int lds_uint;
static __device__ __forceinline__ void gload_lds16(const void* g, void* l) {
    __builtin_amdgcn_global_load_lds((glb_uint*)g, (lds_uint*)l, 16, 0, 0);
}

// ---------------------------------------------------------------------------
// Kernel A: per 32-row tile: stage x bf16 -> LDS; waves 0-1: z = proj MFMA,
// waves 2-3: xT transpose writes (concurrent); then MLP pi on all waves.
// Grid 8*64 = 512 (2 blocks/CU), 256 thr.
// ---------------------------------------------------------------------------
__global__ __launch_bounds__(256) void fused_a_kernel(
    const float* __restrict__ x,
    const float* __restrict__ proj_w, const float* __restrict__ proj_b,
    const float* __restrict__ pi_w1,  const float* __restrict__ pi_b1,
    const float* __restrict__ pi_w2,  const float* __restrict__ pi_b2,
    unsigned short* __restrict__ xT,
    unsigned short* __restrict__ zbG,
    float* __restrict__ sqbuf,
    float* __restrict__ pibuf)
{
    const int bid = blockIdx.x;
    const int b = bid & 7, nt = bid >> 3;      // nt 0..63
    const int n0 = nt * 32;
    const int t = threadIdx.x;
    const int wv = t >> 6, ln = t & 63;
    const int kg = ln >> 4, cl = ln & 15;

    const float* xb = x + (size_t)b * NN * FF;
    unsigned short* xTb = xT + (size_t)b * FF * NN;

    __shared__ unsigned short xbsh[32 * 268];   // bf16 x tile (stride 268)
    __shared__ unsigned short Wbsh[16 * 268];   // proj_w bf16 [l][f]
    __shared__ unsigned short W1bsh[256 * 24];  // pi_w1 bf16 [f][l]
    __shared__ unsigned short zbsh[32 * 24];    // z bf16 [n][l]
    __shared__ float b1sh[256], w2sh[256], pbsh[16];
    __shared__ float pp[2][32];

    // ---- stage x tile (f32 -> bf16) ----
#pragma unroll
    for (int i = 0; i < 8; ++i) {
        const int slot = i * 256 + t;
        const int r = slot >> 6, c4 = slot & 63;
        const float4 v = *(const float4*)(xb + (size_t)(n0 + r) * FF + c4 * 4);
        ushort4 o; o.x = f2bf(v.x); o.y = f2bf(v.y); o.z = f2bf(v.z); o.w = f2bf(v.w);
        *(ushort4*)&xbsh[r * 268 + c4 * 4] = o;
    }
    // ---- stage proj_w ----
#pragma unroll
    for (int i = 0; i < 4; ++i) {
        const int slot = i * 256 + t;
        const int l = slot >> 6, c4 = slot & 63;
        const float4 v = *(const float4*)(proj_w + l * FF + c4 * 4);
        ushort4 o; o.x = f2bf(v.x); o.y = f2bf(v.y); o.z = f2bf(v.z); o.w = f2bf(v.w);
        *(ushort4*)&Wbsh[l * 268 + c4 * 4] = o;
    }
    // ---- stage pi_w1 ----
#pragma unroll
    for (int i = 0; i < 4; ++i) {
        const int slot = i * 256 + t;
        const int f = slot >> 2, q = slot & 3;
        const float4 v = *(const float4*)(pi_w1 + f * LL + q * 4);
        ushort4 o; o.x = f2bf(v.x); o.y = f2bf(v.y); o.z = f2bf(v.z); o.w = f2bf(v.w);
        *(ushort4*)&W1bsh[f * 24 + q * 4] = o;
    }
    b1sh[t] = pi_b1[t];
    w2sh[t] = pi_w2[t];
    if (t < 16) pbsh[t] = proj_b[t];
    __syncthreads();

    // ---- wave-specialized: proj MFMA (wv<2) || transpose writes (wv>=2) ----
    if (wv < 2) {
        f32x4 zacc = {0.f, 0.f, 0.f, 0.f};
#pragma unroll
        for (int g = 0; g < 8; ++g) {
            const s16x8 af = *(const s16x8*)&xbsh[(wv * 16 + cl) * 268 + g * 32 + kg * 8];
            const s16x8 bf = *(const s16x8*)&Wbsh[cl * 268 + g * 32 + kg * 8];
            zacc = __builtin_amdgcn_mfma_f32_16x16x32_bf16(af, bf, zacc, 0, 0, 0);
        }
        const float pb = pbsh[cl];
#pragma unroll
        for (int r = 0; r < 4; ++r)
            zbsh[(wv * 16 + kg * 4 + r) * 24 + cl] = f2bf(zacc[r] + pb);
    } else {
        // transpose: wave covers 128 f rows; per inst 8 f-rows x 32n = 64B lines
#pragma unroll
        for (int it = 0; it < 16; ++it) {
            const int f = (wv - 2) * 128 + it * 8 + (ln >> 3);
            const int q = ln & 7;
            ushort4 o;
            o.x = xbsh[(q * 4 + 0) * 268 + f];
            o.y = xbsh[(q * 4 + 1) * 268 + f];
            o.z = xbsh[(q * 4 + 2) * 268 + f];
            o.w = xbsh[(q * 4 + 3) * 268 + f];
            *(ushort4*)(xTb + (size_t)f * NN + n0 + q * 4) = o;
        }
    }
    __syncthreads();

    // ---- z -> global (bf16), sq from bf16 z (exact diagonal) ----
    if (t < 32) {
        unsigned short zr[16]; float sq = 0.f;
#pragma unroll
        for (int l = 0; l < 16; ++l) {
            zr[l] = zbsh[t * 24 + l];
            const float zf = bf2f(zr[l]);
            sq = fmaf(zf, zf, sq);
        }
        unsigned short* dst = zbG + ((size_t)b * NN + n0 + t) * 16;
        *(uint4*)dst = *(uint4*)&zr[0];
        *(uint4*)(dst + 8) = *(uint4*)&zr[8];
        sqbuf[(size_t)b * NN + n0 + t] = sq;
    }

    // ---- MLP via MFMA: wave -> (ntile = wv&1, f-chunk = wv>>1) ----
    {
        const int ntl = wv & 1;
        s16x8 bz = {0, 0, 0, 0, 0, 0, 0, 0};
        if (kg < 2) bz = *(const s16x8*)&zbsh[(ntl * 16 + cl) * 24 + kg * 8];
        float pisum = 0.f;
        const f32x4 zf4 = {0.f, 0.f, 0.f, 0.f};
#pragma unroll
        for (int j = 0; j < 8; ++j) {
            const int ft = (wv >> 1) * 8 + j;
            s16x8 aw = {0, 0, 0, 0, 0, 0, 0, 0};
            if (kg < 2) aw = *(const s16x8*)&W1bsh[(ft * 16 + cl) * 24 + kg * 8];
            const f32x4 h4 = __builtin_amdgcn_mfma_f32_16x16x32_bf16(aw, bz, zf4, 0, 0, 0);
#pragma unroll
            for (int r = 0; r < 4; ++r) {
                const int f = ft * 16 + kg * 4 + r;
                const float h = fmaxf(h4[r] + b1sh[f], 0.f);
                pisum = fmaf(h, w2sh[f], pisum);
            }
        }
        pisum += __shfl_xor(pisum, 16, 64);
        pisum += __shfl_xor(pisum, 32, 64);
        if (ln < 16) pp[wv >> 1][ntl * 16 + ln] = pisum;
    }
    __syncthreads();

    if (t < 32) {
        const float tp = pp[0][t] + pp[1][t] + pi_b2[0];
        pibuf[(size_t)b * NN + n0 + t] = 1.f / (1.f + __expf(-tp));
    }
}

// ---------------------------------------------------------------------------
// Kernel Q: q[n] = sum_m exp(2 z_n.z_m - sq_n - sq_m), gram MFMA fed from
// LDS-staged z (block reads z once). 32n/block, 256thr, grid 512 (2/CU).
// Single barrier per 256-m chunk, dbuf.
// ---------------------------------------------------------------------------
__global__ __launch_bounds__(256) void qc_kernel(
    const unsigned short* __restrict__ zbG,
    const float* __restrict__ sqbuf,
    const float* __restrict__ pibuf,
    float* __restrict__ cbuf)
{
    const int bid = blockIdx.x;
    const int b = bid & 7, nt = bid >> 3;
    const int n0 = nt * 32;
    const int t = threadIdx.x;
    const int wv = t >> 6, ln = t & 63;
    const int kg = ln >> 4, cl = ln & 15;

    const unsigned short* zb = zbG + (size_t)b * NN * LL;
    const float* sqb = sqbuf + (size_t)b * NN;

    __shared__ unsigned short zsh[2][256 * 24];
    __shared__ float sqh[2][256];
    __shared__ float qq[2][32];

    s16x8 zn = {0, 0, 0, 0, 0, 0, 0, 0};
    if (kg < 2) zn = *(const s16x8*)(zb + (size_t)(n0 + (wv & 1) * 16 + cl) * 16 + kg * 8);
    const float sqn = sqb[n0 + (wv & 1) * 16 + cl];
    const f32x4 zf4 = {0.f, 0.f, 0.f, 0.f};
    float qloc = 0.f;

    // prologue: stage chunk 0 (thread t -> row t)
    uint4 za = *(const uint4*)(zb + (size_t)t * 16);
    uint4 zc = *(const uint4*)(zb + (size_t)t * 16 + 8);
    float sv = sqb[t];
    *(uint4*)&zsh[0][t * 24] = za;
    *(uint4*)&zsh[0][t * 24 + 8] = zc;
    sqh[0][t] = sv;
    __syncthreads();

    const int mbase = (wv >> 1) * 128;   // wave's m-half within chunk
    for (int ch = 0; ch < 8; ++ch) {
        const int cur = ch & 1;
        if (ch < 7) {
            const int m = (ch + 1) * 256 + t;
            za = *(const uint4*)(zb + (size_t)m * 16);
            zc = *(const uint4*)(zb + (size_t)m * 16 + 8);
            sv = sqb[m];
        }
#pragma unroll
        for (int mt = 0; mt < 8; ++mt) {
            s16x8 zm = {0, 0, 0, 0, 0, 0, 0, 0};
            if (kg < 2) zm = *(const s16x8*)&zsh[cur][(mbase + mt * 16 + cl) * 24 + kg * 8];
            const f32x4 g = __builtin_amdgcn_mfma_f32_16x16x32_bf16(zm, zn, zf4, 0, 0, 0);
            const f32x4 sq4 = *(const f32x4*)&sqh[cur][mbase + mt * 16 + kg * 4];
#pragma unroll
            for (int r = 0; r < 4; ++r)
                qloc += __expf(2.f * g[r] - sq4[r] - sqn);
        }
        if (ch < 7) {
            *(uint4*)&zsh[cur ^ 1][t * 24] = za;
            *(uint4*)&zsh[cur ^ 1][t * 24 + 8] = zc;
            sqh[cur ^ 1][t] = sv;
        }
        __syncthreads();
    }
    qloc += __shfl_xor(qloc, 16, 64);
    qloc += __shfl_xor(qloc, 32, 64);
    if (ln < 16) qq[wv >> 1][(wv & 1) * 16 + ln] = qloc;
    __syncthreads();
    if (t < 32) {
        const size_t gi = (size_t)b * NN + n0 + t;
        cbuf[gi] = pibuf[gi] / (qq[0][t] + qq[1][t]);
    }
}

// ---------------------------------------------------------------------------
// Kernel M: out[n,f] = (1-dt)x[n,f] + 4dt/(rowsum+1e-5)*sum_m w[n,m]x[m,f]
//   w[n,m] = exp(2 z_n.z_m - sq_n - sq_m)*c[m]  (swapped gram: A=z_m,B=z_n)
// Block: 64n x 128f, 256 thr (4 waves), grid 8*(NN/64)*2 = 512 -> 2 indep
// blocks/CU (independent barrier domains overlap stalls).
// Per 64-m chunk, ONE barrier: P1 gram->exp->wsh[cur]; prefetch z regs +
// c/sq LDS for kt+1; barrier (drains gloads issued LAST chunk); issue
// gload_lds xsh[nxt]; P2 16 MFMA (setprio-wrapped).
// ---------------------------------------------------------------------------
struct ZM { s16x8 z[4]; };

__global__ __launch_bounds__(256) void main_kernel(
    const float* __restrict__ x,
    const unsigned short* __restrict__ xT,
    const unsigned short* __restrict__ zbG,
    const float* __restrict__ sqbuf,
    const float* __restrict__ cbuf,
    const float* __restrict__ dtp,
    float* __restrict__ out)
{
    const int bid = blockIdx.x;
    const int b = bid & 7;
    const int rest = bid >> 3;           // 0..63
    const int fs = rest & 1;             // f-slab
    const int nt = rest >> 1;            // 0..31
    const int n0 = nt * 64, f0 = fs * 128;
    const int t = threadIdx.x;
    const int wv = t >> 6, ln = t & 63;
    const int kg = ln >> 4, cl = ln & 15;

    const float*          xb  = x   + (size_t)b * NN * FF;
    const unsigned short* xTb = xT  + (size_t)b * FF * NN;
    const unsigned short* zb  = zbG + (size_t)b * NN * LL;
    const float*          sqB = sqbuf + (size_t)b * NN;
    const float*          cB  = cbuf  + (size_t)b * NN;
    float*                ob  = out + (size_t)b * NN * FF;

    __shared__ unsigned short xsh[2][128 * 64]; // 32 KB [f][m] 128B rows, XOR swz
    __shared__ unsigned short wsh[2][64 * 64];  // 16 KB [n][m]
    __shared__ float csh[2][64], sqsh[2][64];
    __shared__ float rsp[64];

    const float dtv = dtp[0];
    const int nloc = wv * 16 + cl;       // wave wv owns ntile wv

    s16x8 zn = {0, 0, 0, 0, 0, 0, 0, 0};
    if (kg < 2) zn = *(const s16x8*)(zb + (size_t)(n0 + nloc) * 16 + kg * 8);
    const float sqn = sqB[n0 + nloc];
    const f32x4 zf4 = {0.f, 0.f, 0.f, 0.f};

    f32x4 acc[2][4];
#pragma unroll
    for (int fi = 0; fi < 2; ++fi)
#pragma unroll
        for (int ni = 0; ni < 4; ++ni) acc[fi][ni] = (f32x4){0.f, 0.f, 0.f, 0.f};
    float rloc = 0.f;

    auto loadZM = [&](ZM& Z, int kt) {
        const int m0 = kt * 64;
#pragma unroll
        for (int mt = 0; mt < 4; ++mt) {
            Z.z[mt] = (s16x8){0, 0, 0, 0, 0, 0, 0, 0};
            if (kg < 2)
                Z.z[mt] = *(const s16x8*)(zb + (size_t)(m0 + mt * 16 + cl) * 16 + kg * 8);
        }
    };
    auto STAGE_CS = [&](int buf, int kt) {
        const int m0 = kt * 64;
        if (t < 64)        csh[buf][t]       = cB[m0 + t];
        else if (t < 128)  sqsh[buf][t - 64] = sqB[m0 + t - 64];
    };
    auto ISSUE = [&](int buf, int kt) {
        const int m0 = kt * 64;
        char* dst = (char*)&xsh[buf][0];
#pragma unroll
        for (int i = 0; i < 4; ++i) {
            const int fl = (i * 4 + wv) * 8 + (ln >> 3);
            const int cp = ln & 7;
            const int clog = cp ^ (fl & 7);
            const unsigned short* src = xTb + (size_t)(f0 + fl) * NN + m0 + clog * 8;
            gload_lds16(src, dst + (i * 4 + wv) * 1024);
        }
    };
    auto P1 = [&](const ZM& Z, int cur) {
        char* wb = (char*)&wsh[cur][0];
#pragma unroll
        for (int mt = 0; mt < 4; ++mt) {
            const f32x4 g = __builtin_amdgcn_mfma_f32_16x16x32_bf16(Z.z[mt], zn, zf4, 0, 0, 0);
            const f32x4 sq4 = *(const f32x4*)&sqsh[cur][mt * 16 + kg * 4];
            const f32x4 cm4 = *(const f32x4*)&csh[cur][mt * 16 + kg * 4];
            const float w0 = __expf(2.f * g[0] - sq4[0] - sqn) * cm4[0];
            const float w1 = __expf(2.f * g[1] - sq4[1] - sqn) * cm4[1];
            const float w2 = __expf(2.f * g[2] - sq4[2] - sqn) * cm4[2];
            const float w3 = __expf(2.f * g[3] - sq4[3] - sqn) * cm4[3];
            rloc += (w0 + w1) + (w2 + w3);
            uint2 val;
            val.x = (unsigned)f2bf(w0) | ((unsigned)f2bf(w1) << 16);
            val.y = (unsigned)f2bf(w2) | ((unsigned)f2bf(w3) << 16);
            const int c16 = mt * 2 + (kg >> 1);
            const int phys = c16 ^ (nloc & 7);
            *(uint2*)(wb + nloc * 128 + phys * 16 + (kg & 1) * 8) = val;
        }
    };
    auto P2 = [&](int cur) {
        const char* xbuf = (const char*)&xsh[cur][0];
        const char* wbuf = (const char*)&wsh[cur][0];
#pragma unroll
        for (int ks = 0; ks < 2; ++ks) {
            s16x8 a[2], bw[4];
#pragma unroll
            for (int fi = 0; fi < 2; ++fi) {
                const int fl = wv * 32 + fi * 16 + cl;
                const int slot = (ks * 4 + kg) ^ (fl & 7);
                a[fi] = *(const s16x8*)(xbuf + fl * 128 + slot * 16);
            }
#pragma unroll
            for (int ni = 0; ni < 4; ++ni) {
                const int nr = ni * 16 + cl;
                const int slot = (ks * 4 + kg) ^ (nr & 7);
                bw[ni] = *(const s16x8*)(wbuf + nr * 128 + slot * 16);
            }
#pragma unroll
            for (int fi = 0; fi < 2; ++fi)
#pragma unroll
                for (int ni = 0; ni < 4; ++ni)
                    acc[fi][ni] = __builtin_amdgcn_mfma_f32_16x16x32_bf16(
                        a[fi], bw[ni], acc[fi][ni], 0, 0, 0);
        }
    };

    // ---------------- prologue ----------------
    ZM zA, zB;
    STAGE_CS(0, 0);
    loadZM(zA, 0);
    ISSUE(0, 0);
    __syncthreads();

    for (int kt = 0; kt < 32; kt += 2) {
        // even chunk: cur = 0
        P1(zA, 0);
        { loadZM(zB, kt + 1); STAGE_CS(1, kt + 1); }
        __syncthreads();
        ISSUE(1, kt + 1);
        __builtin_amdgcn_s_setprio(1);
        P2(0);
        __builtin_amdgcn_s_setprio(0);
        // odd chunk: cur = 1
        P1(zB, 1);
        if (kt + 2 < 32) { loadZM(zA, kt + 2); STAGE_CS(0, kt + 2); }
        __syncthreads();
        if (kt + 2 < 32) ISSUE(0, kt + 2);
        __builtin_amdgcn_s_setprio(1);
        P2(1);
        __builtin_amdgcn_s_setprio(0);
    }

    // ---- rowsum: reduce across the 4 kg groups (each holds 4 m-rows) ----
    rloc += __shfl_xor(rloc, 16, 64);
    rloc += __shfl_xor(rloc, 32, 64);
    if (ln < 16) rsp[wv * 16 + ln] = rloc;
    __syncthreads();

    // ---- epilogue: D[row=f][col=n] ----
#pragma unroll
    for (int ni = 0; ni < 4; ++ni) {
        const int nl = ni * 16 + cl;
        const float sc = 4.f * dtv / (rsp[nl] + 1e-5f);
        const int ng = n0 + nl;
#pragma unroll
        for (int fi = 0; fi < 2; ++fi) {
            const int fg = f0 + wv * 32 + fi * 16 + kg * 4;
            const float4 xv = *(const float4*)(xb + (size_t)ng * FF + fg);
            float4 o;
            o.x = (1.f - dtv) * xv.x + sc * acc[fi][ni][0];
            o.y = (1.f - dtv) * xv.y + sc * acc[fi][ni][1];
            o.z = (1.f - dtv) * xv.z + sc * acc[fi][ni][2];
            o.w = (1.f - dtv) * xv.w + sc * acc[fi][ni][3];
            *(float4*)(ob + (size_t)ng * FF + fg) = o;
        }
    }
}

// ---------------------------------------------------------------------------
extern "C" void kernel_launch(void* const* d_in, const int* in_sizes, int n_in,
                              void* d_out, int out_size, void* d_ws, size_t ws_size,
                              hipStream_t stream) {
    const float* x      = (const float*)d_in[0];
    const float* proj_w = (const float*)d_in[1];
    const float* proj_b = (const float*)d_in[2];
    const float* pi_w1  = (const float*)d_in[3];
    const float* pi_b1  = (const float*)d_in[4];
    const float* pi_w2  = (const float*)d_in[5];
    const float* pi_b2  = (const float*)d_in[6];
    const float* dtp    = (const float*)d_in[7];
    float* out = (float*)d_out;

    // workspace: xT bf16 8MB | z bf16 512KB | sq 64KB | pi 64KB | c 64KB
    unsigned short* xT  = (unsigned short*)d_ws;
    unsigned short* zbG = xT + (size_t)BATCH * FF * NN;
    float* sqbuf = (float*)(zbG + (size_t)BATCH * NN * LL);
    float* pibuf = sqbuf + (size_t)BATCH * NN;
    float* cbuf  = pibuf + (size_t)BATCH * NN;

    fused_a_kernel<<<dim3(BATCH * (NN / 32)), dim3(256), 0, stream>>>(
        x, proj_w, proj_b, pi_w1, pi_b1, pi_w2, pi_b2, xT, zbG, sqbuf, pibuf);

    qc_kernel<<<dim3(BATCH * (NN / 32)), dim3(256), 0, stream>>>(
        zbG, sqbuf, pibuf, cbuf);

    // 64-row n-tiles x 2 f-slabs: grid = 8 * (2048/64) * 2 = 512  (bug fix:
    // round-5 launched NN/32 here -> nt overran N and faulted)
    main_kernel<<<dim3(BATCH * (NN / 64) * 2), dim3(256), 0, stream>>>(
        x, xT, zbG, sqbuf, cbuf, dtp, out);
}